// Round 2
// baseline (95.742 us; speedup 1.0000x reference)
//
#include <hip/hip_runtime.h>

#define ENT_GRID 16
#define ENT_DIM  64
#define EMB      1024   // ENT_GRID * ENT_DIM
#define LN_EPS   1e-5f
#define NXCD     8

// ---------- sort-by-relation-id machinery (all device-side, capture-safe) ----------

__global__ void zero_hist_kernel(int* __restrict__ hist, int n) {
    int i = blockIdx.x * blockDim.x + threadIdx.x;
    if (i < n) hist[i] = 0;
}

__global__ void hist_kernel(const int* __restrict__ ids, int* __restrict__ hist, int B) {
    int i = blockIdx.x * blockDim.x + threadIdx.x;
    if (i < B) atomicAdd(&hist[ids[i]], 1);
}

// Single-block exclusive scan of hist[0..n) -> cursor[0..n). n <= 8192.
__global__ __launch_bounds__(1024)
void scan_kernel(const int* __restrict__ hist, int* __restrict__ cursor, int n) {
    const int t = threadIdx.x;
    const int ITEMS = (n + 1023) / 1024;   // <= 8
    int vals[8];
    int lsum = 0;
#pragma unroll
    for (int k = 0; k < 8; ++k) {
        int i = t * ITEMS + k;
        int v = (k < ITEMS && i < n) ? hist[i] : 0;
        vals[k] = v;
        lsum += v;
    }
    __shared__ int s[1024];
    s[t] = lsum;
    __syncthreads();
    for (int off = 1; off < 1024; off <<= 1) {
        int v = (t >= off) ? s[t - off] : 0;
        __syncthreads();
        s[t] += v;
        __syncthreads();
    }
    int run = s[t] - lsum;                 // exclusive prefix of this thread's chunk
#pragma unroll
    for (int k = 0; k < 8; ++k) {
        int i = t * ITEMS + k;
        if (k < ITEMS && i < n) cursor[i] = run;
        run += vals[k];
    }
}

__global__ void scatter_kernel(const int* __restrict__ ids, int* __restrict__ cursor,
                               int* __restrict__ perm, int B) {
    int i = blockIdx.x * blockDim.x + threadIdx.x;
    if (i < B) {
        int pos = atomicAdd(&cursor[ids[i]], 1);
        perm[pos] = i;   // batch rows sorted by relation id
    }
}

// ---------- main fused kernel ----------
// One block per batch row (in id-sorted order). 256 threads; each thread
// produces 4 of the 1024 outputs. Embedding row staged in LDS. Fused LayerNorm.
__global__ __launch_bounds__(256, 4)
void wproj_ln_kernel(const float* __restrict__ ent_emb,
                     const float* __restrict__ rel_tran,
                     const float* __restrict__ rel_bias,
                     const float* __restrict__ ln_w,
                     const float* __restrict__ ln_b,
                     const int*   __restrict__ proj_ids,
                     const int*   __restrict__ perm,
                     float* __restrict__ out,
                     int nblk_per_xcd, int use_swizzle) {
    int g = blockIdx.x;
    if (use_swizzle) {
        // HW round-robins blockIdx across 8 XCDs; this maps each XCD's block
        // sequence to a CONTIGUOUS range of sorted positions -> same-relation
        // blocks run temporally adjacent on one XCD (L2/L3 hits).
        g = (g % NXCD) * nblk_per_xcd + g / NXCD;
    }
    const int b = perm[g];
    const int t = threadIdx.x;

    const long long r = (long long)proj_ids[b];
    const float* __restrict__ tran = rel_tran + (size_t)r * (ENT_DIM * ENT_GRID * ENT_GRID);
    const float* __restrict__ bias = rel_bias + (size_t)r * (ENT_DIM * ENT_GRID);
    const float* __restrict__ e    = ent_emb  + (size_t)b * EMB;

    __shared__ float se[EMB];
    __shared__ float wsum[4], wsq[4];

    reinterpret_cast<float4*>(se)[t] = reinterpret_cast<const float4*>(e)[t];
    __syncthreads();

    float x[4];
    float sum = 0.0f, sumsq = 0.0f;

#pragma unroll
    for (int k = 0; k < 4; ++k) {
        const int i = t + k * 256;
        const int d = i >> 4;
        const float4* __restrict__ tr = reinterpret_cast<const float4*>(tran + (size_t)i * ENT_GRID);
        const float4* __restrict__ er = reinterpret_cast<const float4*>(se + d * ENT_GRID);
        float acc = bias[i];
#pragma unroll
        for (int q = 0; q < 4; ++q) {
            float4 a  = tr[q];
            float4 ev = er[q];
            acc += a.x * ev.x + a.y * ev.y + a.z * ev.z + a.w * ev.w;
        }
        x[k]  = acc;
        sum   += acc;
        sumsq += acc * acc;
    }

#pragma unroll
    for (int off = 32; off > 0; off >>= 1) {
        sum   += __shfl_xor(sum, off, 64);
        sumsq += __shfl_xor(sumsq, off, 64);
    }
    const int wid = t >> 6;
    if ((t & 63) == 0) { wsum[wid] = sum; wsq[wid] = sumsq; }
    __syncthreads();

    const float tsum = wsum[0] + wsum[1] + wsum[2] + wsum[3];
    const float tsq  = wsq[0]  + wsq[1]  + wsq[2]  + wsq[3];
    const float mu   = tsum * (1.0f / (float)EMB);
    const float var  = tsq * (1.0f / (float)EMB) - mu * mu;
    const float rstd = rsqrtf(var + LN_EPS);

    float* __restrict__ ob = out + (size_t)b * EMB;
#pragma unroll
    for (int k = 0; k < 4; ++k) {
        const int i = t + k * 256;
        ob[i] = (x[k] - mu) * rstd * ln_w[i] + ln_b[i];
    }
}

extern "C" void kernel_launch(void* const* d_in, const int* in_sizes, int n_in,
                              void* d_out, int out_size, void* d_ws, size_t ws_size,
                              hipStream_t stream) {
    const float* ent_emb  = (const float*)d_in[0];
    const int*   proj_ids = (const int*)  d_in[1];
    const float* rel_tran = (const float*)d_in[2];
    const float* rel_bias = (const float*)d_in[3];
    const float* ln_w     = (const float*)d_in[4];
    const float* ln_b     = (const float*)d_in[5];
    float* out = (float*)d_out;

    const int B  = in_sizes[1];                       // 8192 batch rows
    const int NR = in_sizes[2] / (ENT_DIM * ENT_GRID * ENT_GRID);  // 5000 relations

    int* w      = (int*)d_ws;
    int* hist   = w;            // [NR]
    int* cursor = w + NR;       // [NR]
    int* perm   = w + 2 * NR;   // [B]

    zero_hist_kernel<<<(NR + 255) / 256, 256, 0, stream>>>(hist, NR);
    hist_kernel<<<(B + 255) / 256, 256, 0, stream>>>(proj_ids, hist, B);
    scan_kernel<<<1, 1024, 0, stream>>>(hist, cursor, NR);
    scatter_kernel<<<(B + 255) / 256, 256, 0, stream>>>(proj_ids, cursor, perm, B);

    const int use_swizzle = (B % NXCD == 0) ? 1 : 0;
    wproj_ln_kernel<<<B, 256, 0, stream>>>(ent_emb, rel_tran, rel_bias, ln_w, ln_b,
                                           proj_ids, perm, out, B / NXCD, use_swizzle);
}

// Round 3
// 90.511 us; speedup vs baseline: 1.0578x; 1.0578x over previous
//
#include <hip/hip_runtime.h>

#define ENT_GRID 16
#define ENT_DIM  64
#define EMB      1024   // ENT_GRID * ENT_DIM
#define LN_EPS   1e-5f

// ---------- sort-by-relation-id machinery (device-side, capture-safe) ----------

__global__ void zero_hist_kernel(int* __restrict__ hist, int n) {
    int i = blockIdx.x * blockDim.x + threadIdx.x;
    if (i < n) hist[i] = 0;
}

__global__ void hist_kernel(const int* __restrict__ ids, int* __restrict__ hist, int B) {
    int i = blockIdx.x * blockDim.x + threadIdx.x;
    if (i < B) atomicAdd(&hist[ids[i]], 1);
}

// Single-block exclusive scan of hist[0..n) -> cursor[0..n). n <= 8192.
__global__ __launch_bounds__(1024)
void scan_kernel(const int* __restrict__ hist, int* __restrict__ cursor, int n) {
    const int t = threadIdx.x;
    const int ITEMS = (n + 1023) / 1024;   // <= 8
    int vals[8];
    int lsum = 0;
#pragma unroll
    for (int k = 0; k < 8; ++k) {
        int i = t * ITEMS + k;
        int v = (k < ITEMS && i < n) ? hist[i] : 0;
        vals[k] = v;
        lsum += v;
    }
    __shared__ int s[1024];
    s[t] = lsum;
    __syncthreads();
    for (int off = 1; off < 1024; off <<= 1) {
        int v = (t >= off) ? s[t - off] : 0;
        __syncthreads();
        s[t] += v;
        __syncthreads();
    }
    int run = s[t] - lsum;
#pragma unroll
    for (int k = 0; k < 8; ++k) {
        int i = t * ITEMS + k;
        if (k < ITEMS && i < n) cursor[i] = run;
        run += vals[k];
    }
}

__global__ void scatter_kernel(const int* __restrict__ ids, int* __restrict__ cursor,
                               int* __restrict__ perm, int B) {
    int i = blockIdx.x * blockDim.x + threadIdx.x;
    if (i < B) {
        int pos = atomicAdd(&cursor[ids[i]], 1);
        perm[pos] = i;
    }
    // after this kernel: cursor[r] == END offset of group r; start = cursor[r]-hist[r]
}

// ---------- main kernel: one block PER RELATION, tran row held in registers ----------
// Each thread owns outputs i = t + k*256 (k=0..3): 4 tran rows of 16 floats
// = 16 float4 regs, loaded ONCE. Then loop over the group's batch rows:
// stage emb in LDS, 4 dot products, fused LayerNorm, write.
__global__ __launch_bounds__(256, 4)
void wproj_group_kernel(const float* __restrict__ ent_emb,
                        const float* __restrict__ rel_tran,
                        const float* __restrict__ rel_bias,
                        const float* __restrict__ ln_w,
                        const float* __restrict__ ln_b,
                        const int*   __restrict__ hist,
                        const int*   __restrict__ cursor_end,
                        const int*   __restrict__ perm,
                        float* __restrict__ out) {
    const int r   = blockIdx.x;
    const int cnt = hist[r];
    if (cnt == 0) return;
    const int start = cursor_end[r] - cnt;
    const int t = threadIdx.x;

    const float* __restrict__ tran = rel_tran + (size_t)r * (ENT_DIM * ENT_GRID * ENT_GRID);
    const float* __restrict__ bias = rel_bias + (size_t)r * (ENT_DIM * ENT_GRID);

    float4 trv[4][4];            // 64 VGPRs: this thread's 4 tran rows (16 f each)
    float  bias_v[4], lw[4], lb[4];
#pragma unroll
    for (int k = 0; k < 4; ++k) {
        const int i = t + k * 256;
        const float4* __restrict__ trp = reinterpret_cast<const float4*>(tran + (size_t)i * ENT_GRID);
#pragma unroll
        for (int q = 0; q < 4; ++q) trv[k][q] = trp[q];
        bias_v[k] = bias[i];
        lw[k] = ln_w[i];
        lb[k] = ln_b[i];
    }

    __shared__ float se[EMB];
    __shared__ float wsum[4], wsq[4];

    for (int j = 0; j < cnt; ++j) {
        const int b = perm[start + j];

        reinterpret_cast<float4*>(se)[t] =
            reinterpret_cast<const float4*>(ent_emb + (size_t)b * EMB)[t];
        __syncthreads();

        float x[4];
        float sum = 0.0f, sumsq = 0.0f;
#pragma unroll
        for (int k = 0; k < 4; ++k) {
            const int d = (t >> 4) + k * 16;
            const float4* __restrict__ er = reinterpret_cast<const float4*>(se + d * ENT_GRID);
            float acc = bias_v[k];
#pragma unroll
            for (int q = 0; q < 4; ++q) {
                float4 a  = trv[k][q];
                float4 ev = er[q];
                acc += a.x * ev.x + a.y * ev.y + a.z * ev.z + a.w * ev.w;
            }
            x[k]  = acc;
            sum   += acc;
            sumsq += acc * acc;
        }

#pragma unroll
        for (int off = 32; off > 0; off >>= 1) {
            sum   += __shfl_xor(sum, off, 64);
            sumsq += __shfl_xor(sumsq, off, 64);
        }
        const int wid = t >> 6;
        if ((t & 63) == 0) { wsum[wid] = sum; wsq[wid] = sumsq; }
        __syncthreads();

        const float tsum = wsum[0] + wsum[1] + wsum[2] + wsum[3];
        const float tsq  = wsq[0]  + wsq[1]  + wsq[2]  + wsq[3];
        const float mu   = tsum * (1.0f / (float)EMB);
        const float var  = tsq * (1.0f / (float)EMB) - mu * mu;
        const float rstd = rsqrtf(var + LN_EPS);

        float* __restrict__ ob = out + (size_t)b * EMB;
#pragma unroll
        for (int k = 0; k < 4; ++k) {
            const int i = t + k * 256;
            ob[i] = (x[k] - mu) * rstd * lw[k] + lb[k];
        }
        __syncthreads();   // se reused next iteration
    }
}

extern "C" void kernel_launch(void* const* d_in, const int* in_sizes, int n_in,
                              void* d_out, int out_size, void* d_ws, size_t ws_size,
                              hipStream_t stream) {
    const float* ent_emb  = (const float*)d_in[0];
    const int*   proj_ids = (const int*)  d_in[1];
    const float* rel_tran = (const float*)d_in[2];
    const float* rel_bias = (const float*)d_in[3];
    const float* ln_w     = (const float*)d_in[4];
    const float* ln_b     = (const float*)d_in[5];
    float* out = (float*)d_out;

    const int B  = in_sizes[1];                                     // 8192
    const int NR = in_sizes[2] / (ENT_DIM * ENT_GRID * ENT_GRID);   // 5000

    int* w      = (int*)d_ws;
    int* hist   = w;            // [NR]
    int* cursor = w + NR;       // [NR]
    int* perm   = w + 2 * NR;   // [B]

    zero_hist_kernel<<<(NR + 255) / 256, 256, 0, stream>>>(hist, NR);
    hist_kernel<<<(B + 255) / 256, 256, 0, stream>>>(proj_ids, hist, B);
    scan_kernel<<<1, 1024, 0, stream>>>(hist, cursor, NR);
    scatter_kernel<<<(B + 255) / 256, 256, 0, stream>>>(proj_ids, cursor, perm, B);

    wproj_group_kernel<<<NR, 256, 0, stream>>>(ent_emb, rel_tran, rel_bias, ln_w, ln_b,
                                               hist, cursor, perm, out);
}